// Round 1
// baseline (224.011 us; speedup 1.0000x reference)
//
#include <hip/hip_runtime.h>
#include <math.h>

#define B_N 2048
#define D_FT 784
#define K_N 50
#define L_N 6
#define LOG2PI_F 1.8378770664093453f

// ---- output layout (floats), concatenated in reference return order ----
#define OUT_PW 0
#define OUT_M  (B_N)                              // 2048
#define OUT_A  (OUT_M + B_N*D_FT)                 // 1607680
#define OUT_D  (OUT_A + B_N*D_FT*6)               // 11241472

// ---- workspace layout (float offsets) ----
#define WS_SCORES 0                                // [K][B]     102400
#define WS_PQ     (WS_SCORES + K_N*B_N)            // [K][27][B] 2764800
#define WS_C      (WS_PQ + K_N*27*B_N)             // [B] int    2048
#define WS_MZLZ   (WS_C + B_N)                     // [B][28]    57344
#define WS_XT     (WS_MZLZ + B_N*28)               // [D][B]     1605632
#define WS_JBT    (WS_XT + D_FT*B_N)               // [25][B]    51200
#define WS_TOTAL  (WS_JBT + 25*B_N)                // = 4,583,424 floats = 18.3 MB

#define IDX(i,j) ((i)*((i)+1)/2 + (j))   // packed lower, i>=j

// ---------- 6x6 packed-lower Cholesky ----------
__device__ __forceinline__ void chol6(const float* P, float* L, float* rd, float* sumlog) {
    float sl = 0.f;
    #pragma unroll
    for (int j = 0; j < 6; ++j) {
        float s = P[IDX(j,j)];
        #pragma unroll
        for (int m = 0; m < j; ++m) s -= L[IDX(j,m)] * L[IDX(j,m)];
        float d = sqrtf(s);
        L[IDX(j,j)] = d;
        float r = 1.0f / d;
        rd[j] = r;
        sl += logf(d);
        #pragma unroll
        for (int i = j + 1; i < 6; ++i) {
            float t = P[IDX(i,j)];
            #pragma unroll
            for (int m = 0; m < j; ++m) t -= L[IDX(i,m)] * L[IDX(j,m)];
            L[IDX(i,j)] = t * r;
        }
    }
    *sumlog = sl;
}

// ---------- K0: transpose X [B][D] -> Xt [D][B] ----------
__global__ void k_transpose(const float* __restrict__ X, float* __restrict__ Xt) {
    __shared__ float tile[32][33];
    int d = blockIdx.x * 32 + threadIdx.x;
    int b = blockIdx.y * 32 + threadIdx.y;
    if (d < D_FT) tile[threadIdx.y][threadIdx.x] = X[(size_t)b * D_FT + d];
    __syncthreads();
    int bo = blockIdx.y * 32 + threadIdx.x;
    int do_ = blockIdx.x * 32 + threadIdx.y;
    if (do_ < D_FT) Xt[(size_t)do_ * B_N + bo] = tile[threadIdx.x][threadIdx.y];
}

// ---------- K0b: pack J bits -> JbT[w][b], w in [0,25) ----------
__global__ void k_packbits(const int* __restrict__ J, unsigned* __restrict__ JbT) {
    int t = blockIdx.x * blockDim.x + threadIdx.x;   // 2048*32 threads
    int b = t >> 5;
    int w = t & 31;
    if (w >= 25) return;
    int d0 = w * 32;
    int n = D_FT - d0; if (n > 32) n = 32;
    unsigned u = 0;
    for (int j = 0; j < n; ++j)
        u |= (J[(size_t)b * D_FT + d0 + j] != 0 ? 1u : 0u) << j;
    JbT[(size_t)w * B_N + b] = u;
}

// ---------- K1: per-(sample,k) accumulation + loglik ----------
__global__ __launch_bounds__(128) void k_accum(
        const float* __restrict__ Xt, const unsigned* __restrict__ JbT,
        const float* __restrict__ A, const float* __restrict__ MU,
        const float* __restrict__ logD, const float* __restrict__ PI,
        float* __restrict__ scores, float* __restrict__ Pq) {
    __shared__ float rec[D_FT * 12];   // per d: A0..A5, invD, logD, mu, pad3
    const int k = blockIdx.x >> 4;
    const int b = (blockIdx.x & 15) * 128 + threadIdx.x;

    for (int i = threadIdx.x; i < D_FT; i += 128) {
        const float* ar = A + ((size_t)k * D_FT + i) * 6;
        float* r = &rec[i * 12];
        #pragma unroll
        for (int t = 0; t < 6; ++t) r[t] = ar[t];
        float ld = logD[(size_t)k * D_FT + i];
        r[6] = expf(-ld);
        r[7] = ld;
        r[8] = MU[(size_t)k * D_FT + i];
    }
    __syncthreads();

    float Pm[21], qv[6];
    #pragma unroll
    for (int t = 0; t < 21; ++t) Pm[t] = 0.f;
    #pragma unroll
    for (int t = 0; t < 6; ++t) qv[t] = 0.f;
    float quad = 0.f, jld = 0.f, nobs = 0.f;

    for (int w = 0; w < 25; ++w) {
        unsigned mword = JbT[(size_t)w * B_N + b];
        int dmax = D_FT - w * 32; if (dmax > 32) dmax = 32;
        for (int dd0 = 0; dd0 < dmax; dd0 += 4) {
            #pragma unroll
            for (int u = 0; u < 4; ++u) {
                int dd = dd0 + u;
                int d = w * 32 + dd;
                float x = Xt[(size_t)d * B_N + b];
                const float* r = &rec[d * 12];
                float mf = (float)((mword >> dd) & 1u);
                float a0 = r[0], a1 = r[1], a2 = r[2], a3 = r[3], a4 = r[4], a5 = r[5];
                float iD = r[6], lD = r[7], mu = r[8];
                float xm = x - mu;
                float md = mf * xm;
                float wg = mf * iD;
                float u0 = wg*a0, u1 = wg*a1, u2 = wg*a2, u3 = wg*a3, u4 = wg*a4, u5 = wg*a5;
                Pm[0]  += u0*a0;
                Pm[1]  += u1*a0; Pm[2]  += u1*a1;
                Pm[3]  += u2*a0; Pm[4]  += u2*a1; Pm[5]  += u2*a2;
                Pm[6]  += u3*a0; Pm[7]  += u3*a1; Pm[8]  += u3*a2; Pm[9]  += u3*a3;
                Pm[10] += u4*a0; Pm[11] += u4*a1; Pm[12] += u4*a2; Pm[13] += u4*a3; Pm[14] += u4*a4;
                Pm[15] += u5*a0; Pm[16] += u5*a1; Pm[17] += u5*a2; Pm[18] += u5*a3; Pm[19] += u5*a4; Pm[20] += u5*a5;
                qv[0] += md*u0; qv[1] += md*u1; qv[2] += md*u2;
                qv[3] += md*u3; qv[4] += md*u4; qv[5] += md*u5;
                float t = wg * md;
                quad += t * md;
                jld  += mf * lD;
                nobs += mf;
            }
        }
    }

    // P = I + sum
    Pm[0] += 1.f; Pm[2] += 1.f; Pm[5] += 1.f; Pm[9] += 1.f; Pm[14] += 1.f; Pm[20] += 1.f;

    float Lm[21], rd[6], sumlog;
    chol6(Pm, Lm, rd, &sumlog);
    float y[6];
    #pragma unroll
    for (int j = 0; j < 6; ++j) {
        float s = qv[j];
        #pragma unroll
        for (int m = 0; m < j; ++m) s -= Lm[IDX(j,m)] * y[m];
        y[j] = s * rd[j];
    }
    float yy = 0.f;
    #pragma unroll
    for (int j = 0; j < 6; ++j) yy += y[j] * y[j];
    float logdet = 2.f * sumlog + jld;
    float ll = -0.5f * ((quad - yy) + logdet + nobs * LOG2PI_F);
    float score = ll + PI[k];

    scores[(size_t)k * B_N + b] = score;
    float* pq = Pq + (size_t)k * 27 * B_N + b;
    #pragma unroll
    for (int t = 0; t < 21; ++t) pq[(size_t)t * B_N] = Pm[t];
    #pragma unroll
    for (int t = 0; t < 6; ++t) pq[(size_t)(21 + t) * B_N] = qv[t];
}

// ---------- KC: argmax + latent solve per sample ----------
__global__ void k_select(const float* __restrict__ scores, const float* __restrict__ Pq,
                         int* __restrict__ csel, float* __restrict__ mzLz,
                         float* __restrict__ out) {
    int b = blockIdx.x * blockDim.x + threadIdx.x;
    if (b >= B_N) return;

    float best = scores[b];
    int bc = 0;
    for (int k = 1; k < K_N; ++k) {
        float s = scores[(size_t)k * B_N + b];
        if (s > best) { best = s; bc = k; }
    }
    csel[b] = bc;
    out[OUT_PW + b] = 1.0f;

    float Pm[21], qv[6];
    const float* pq = Pq + (size_t)bc * 27 * B_N + b;
    #pragma unroll
    for (int t = 0; t < 21; ++t) Pm[t] = pq[(size_t)t * B_N];
    #pragma unroll
    for (int t = 0; t < 6; ++t) qv[t] = pq[(size_t)(21 + t) * B_N];

    float Lm[21], rd[6], dummy;
    chol6(Pm, Lm, rd, &dummy);

    // forward: L y = q
    float y[6];
    #pragma unroll
    for (int j = 0; j < 6; ++j) {
        float s = qv[j];
        #pragma unroll
        for (int m = 0; m < j; ++m) s -= Lm[IDX(j,m)] * y[m];
        y[j] = s * rd[j];
    }
    // backward: L^T mz = y
    float mz[6];
    #pragma unroll
    for (int ii = 5; ii >= 0; --ii) {
        float s = y[ii];
        #pragma unroll
        for (int j = ii + 1; j < 6; ++j) s -= Lm[IDX(j,ii)] * mz[j];
        mz[ii] = s * rd[ii];
    }
    // Linv (packed lower)
    float Li[21];
    #pragma unroll
    for (int j = 0; j < 6; ++j) {
        Li[IDX(j,j)] = rd[j];
        #pragma unroll
        for (int i = j + 1; i < 6; ++i) {
            float s = 0.f;
            #pragma unroll
            for (int m = j; m < i; ++m) s += Lm[IDX(i,m)] * Li[IDX(m,j)];
            Li[IDX(i,j)] = -s * rd[i];
        }
    }
    // cov = Linv^T Linv (packed lower)
    float cov[21];
    #pragma unroll
    for (int i = 0; i < 6; ++i) {
        #pragma unroll
        for (int j = 0; j <= i; ++j) {
            float s = 0.f;
            #pragma unroll
            for (int m = i; m < 6; ++m) s += Li[IDX(m,i)] * Li[IDX(m,j)];
            cov[IDX(i,j)] = s;
        }
    }
    float Lz[21], rd2[6];
    chol6(cov, Lz, rd2, &dummy);

    float* o = mzLz + (size_t)b * 28;
    #pragma unroll
    for (int t = 0; t < 6; ++t) o[t] = mz[t];
    #pragma unroll
    for (int t = 0; t < 21; ++t) o[6 + t] = Lz[t];
}

// ---------- KD: write M, A_out, D_out ----------
__global__ __launch_bounds__(256) void k_output(
        const float* __restrict__ A, const float* __restrict__ MU,
        const float* __restrict__ logD, const int* __restrict__ csel,
        const float* __restrict__ mzLz, float* __restrict__ out) {
    __shared__ float smz[6];
    __shared__ float sLz[21];
    __shared__ int sc;
    int b = blockIdx.x;
    if (threadIdx.x == 0) sc = csel[b];
    if (threadIdx.x < 27) {
        float v = mzLz[(size_t)b * 28 + threadIdx.x];
        if (threadIdx.x < 6) smz[threadIdx.x] = v;
        else sLz[threadIdx.x - 6] = v;
    }
    __syncthreads();
    int c = sc;

    for (int d = threadIdx.x; d < D_FT; d += 256) {
        const float* ar = A + ((size_t)c * D_FT + d) * 6;
        float a[6];
        #pragma unroll
        for (int i = 0; i < 6; ++i) a[i] = ar[i];
        float mu = MU[(size_t)c * D_FT + d];
        float ld = logD[(size_t)c * D_FT + d];
        float m = mu;
        #pragma unroll
        for (int i = 0; i < 6; ++i) m += a[i] * smz[i];
        out[OUT_M + (size_t)b * D_FT + d] = m;
        out[OUT_D + (size_t)b * D_FT + d] = expf(ld);
        float* ao = out + OUT_A + ((size_t)b * D_FT + d) * 6;
        #pragma unroll
        for (int j = 0; j < 6; ++j) {
            float s = 0.f;
            #pragma unroll
            for (int i = j; i < 6; ++i) s += a[i] * sLz[IDX(i,j)];
            ao[j] = s;
        }
    }
}

extern "C" void kernel_launch(void* const* d_in, const int* in_sizes, int n_in,
                              void* d_out, int out_size, void* d_ws, size_t ws_size,
                              hipStream_t stream) {
    (void)in_sizes; (void)n_in; (void)out_size; (void)ws_size;
    const float* X    = (const float*)d_in[0];
    const int*   J    = (const int*)d_in[1];
    const float* MU   = (const float*)d_in[2];
    const float* A    = (const float*)d_in[3];
    const float* logD = (const float*)d_in[4];
    const float* PI   = (const float*)d_in[5];
    float* out = (float*)d_out;
    float* ws  = (float*)d_ws;

    float*    scores = ws + WS_SCORES;
    float*    Pq     = ws + WS_PQ;
    int*      csel   = (int*)(ws + WS_C);
    float*    mzLz   = ws + WS_MZLZ;
    float*    Xt     = ws + WS_XT;
    unsigned* JbT    = (unsigned*)(ws + WS_JBT);

    dim3 g0((D_FT + 31) / 32, B_N / 32), b0(32, 32);
    k_transpose<<<g0, b0, 0, stream>>>(X, Xt);

    k_packbits<<<(B_N * 32) / 256, 256, 0, stream>>>(J, JbT);

    k_accum<<<16 * K_N, 128, 0, stream>>>(Xt, JbT, A, MU, logD, PI, scores, Pq);

    k_select<<<B_N / 256, 256, 0, stream>>>(scores, Pq, csel, mzLz, out);

    k_output<<<B_N, 256, 0, stream>>>(A, MU, logD, csel, mzLz, out);
}

// Round 2
// 155.166 us; speedup vs baseline: 1.4437x; 1.4437x over previous
//
#include <hip/hip_runtime.h>
#include <math.h>

#define B_N 2048
#define D_FT 784
#define K_N 50
#define L_N 6
#define LOG2PI_F 1.8378770664093453f

// ---- output layout (floats), concatenated in reference return order ----
#define OUT_PW 0
#define OUT_M  (B_N)                              // 2048
#define OUT_A  (OUT_M + B_N*D_FT)                 // 1607680
#define OUT_D  (OUT_A + B_N*D_FT*6)               // 11241472

// ---- workspace layout (float offsets) ----
#define WS_SCORES 0                                // [K][B]     102400
#define WS_PQ     (WS_SCORES + K_N*B_N)            // [K][27][B] 2764800
#define WS_C      (WS_PQ + K_N*27*B_N)             // [B] int    2048
#define WS_MZLZ   (WS_C + B_N)                     // [B][28]    57344
#define WS_XT     (WS_MZLZ + B_N*28)               // [D/4][B] float4 = D*B floats
#define WS_JBT    (WS_XT + D_FT*B_N)               // [25][B]    51200
#define WS_TOTAL  (WS_JBT + 25*B_N)                // = 4,583,424 floats = 18.3 MB

#define IDX(i,j) ((i)*((i)+1)/2 + (j))   // packed lower, i>=j

// ---------- 6x6 packed-lower Cholesky ----------
__device__ __forceinline__ void chol6(const float* P, float* L, float* rd, float* sumlog) {
    float sl = 0.f;
    #pragma unroll
    for (int j = 0; j < 6; ++j) {
        float s = P[IDX(j,j)];
        #pragma unroll
        for (int m = 0; m < j; ++m) s -= L[IDX(j,m)] * L[IDX(j,m)];
        float d = sqrtf(s);
        L[IDX(j,j)] = d;
        float r = 1.0f / d;
        rd[j] = r;
        sl += logf(d);
        #pragma unroll
        for (int i = j + 1; i < 6; ++i) {
            float t = P[IDX(i,j)];
            #pragma unroll
            for (int m = 0; m < j; ++m) t -= L[IDX(i,m)] * L[IDX(j,m)];
            L[IDX(i,j)] = t * r;
        }
    }
    *sumlog = sl;
}

// ---------- K0: transpose X [B][D] -> Xt4 [D/4][B] (float4 per cell) ----------
__global__ __launch_bounds__(1024) void k_transpose4(const float* __restrict__ X,
                                                     float4* __restrict__ Xt4) {
    __shared__ float4 tile[32][33];
    int tx = threadIdx.x, ty = threadIdx.y;
    int d4b = blockIdx.x * 32;
    int bb  = blockIdx.y * 32;
    int d4 = d4b + tx;
    if (d4 < D_FT / 4)
        tile[ty][tx] = *(const float4*)&X[(size_t)(bb + ty) * D_FT + d4 * 4];
    __syncthreads();
    int d4o = d4b + ty;
    if (d4o < D_FT / 4)
        Xt4[(size_t)d4o * B_N + (bb + tx)] = tile[tx][ty];
}

// ---------- K0b: pack J bits -> JbT[w][b], w in [0,25) ----------
__global__ void k_packbits(const int* __restrict__ J, unsigned* __restrict__ JbT) {
    int t = blockIdx.x * blockDim.x + threadIdx.x;   // 2048*32 threads
    int b = t >> 5;
    int w = t & 31;
    if (w >= 25) return;
    int d0 = w * 32;
    int n = D_FT - d0; if (n > 32) n = 32;
    unsigned u = 0;
    for (int j = 0; j < n; ++j)
        u |= (J[(size_t)b * D_FT + d0 + j] != 0 ? 1u : 0u) << j;
    JbT[(size_t)w * B_N + b] = u;
}

// ---------- K1: per-(sample,k) accumulation + loglik ----------
// 256 threads = 128 samples x 2 d-halves. h=0: words 0..11, h=1: words 12..24.
#define ACC_BODY(dd, xval) do { \
    const int d_ = wbase + (dd); \
    const float* r_ = &smem[d_ * 12]; \
    float mf = (float)((mw >> (dd)) & 1u); \
    float a0=r_[0], a1=r_[1], a2=r_[2], a3=r_[3], a4=r_[4], a5=r_[5]; \
    float giD = mf * r_[6]; \
    float xm = (xval) - r_[8]; \
    float md = mf * xm; \
    jld += mf * r_[7]; \
    float u0=giD*a0, u1=giD*a1, u2=giD*a2, u3=giD*a3, u4=giD*a4, u5=giD*a5; \
    Pm[0]  += u0*a0; \
    Pm[1]  += u1*a0; Pm[2]  += u1*a1; \
    Pm[3]  += u2*a0; Pm[4]  += u2*a1; Pm[5]  += u2*a2; \
    Pm[6]  += u3*a0; Pm[7]  += u3*a1; Pm[8]  += u3*a2; Pm[9]  += u3*a3; \
    Pm[10] += u4*a0; Pm[11] += u4*a1; Pm[12] += u4*a2; Pm[13] += u4*a3; Pm[14] += u4*a4; \
    Pm[15] += u5*a0; Pm[16] += u5*a1; Pm[17] += u5*a2; Pm[18] += u5*a3; Pm[19] += u5*a4; Pm[20] += u5*a5; \
    qv[0] += md*u0; qv[1] += md*u1; qv[2] += md*u2; \
    qv[3] += md*u3; qv[4] += md*u4; qv[5] += md*u5; \
    float tq = md * md; \
    quad += tq * giD; \
} while (0)

__global__ __launch_bounds__(256, 4) void k_accum(
        const float4* __restrict__ Xt4, const unsigned* __restrict__ JbT,
        const float* __restrict__ A, const float* __restrict__ MU,
        const float* __restrict__ logD, const float* __restrict__ PI,
        float* __restrict__ scores, float* __restrict__ Pq) {
    __shared__ float smem[D_FT * 12];   // 37632 B; aliased as reduction buffer later
    const int k   = blockIdx.x >> 4;
    const int tid = threadIdx.x;
    const int s   = tid & 127;
    const int h   = tid >> 7;
    const int b   = (blockIdx.x & 15) * 128 + s;

    for (int i = tid; i < D_FT; i += 256) {
        const float* ar = A + ((size_t)k * D_FT + i) * 6;
        float* r = &smem[i * 12];
        r[0]=ar[0]; r[1]=ar[1]; r[2]=ar[2]; r[3]=ar[3]; r[4]=ar[4]; r[5]=ar[5];
        float ld = logD[(size_t)k * D_FT + i];
        r[6] = expf(-ld);
        r[7] = ld;
        r[8] = MU[(size_t)k * D_FT + i];
    }
    __syncthreads();

    float Pm[21], qv[6];
    #pragma unroll
    for (int t = 0; t < 21; ++t) Pm[t] = 0.f;
    #pragma unroll
    for (int t = 0; t < 6; ++t) qv[t] = 0.f;
    float quad = 0.f, jld = 0.f;
    int nob = 0;

    const int w0 = h ? 12 : 0;
    const int w1 = h ? 24 : 12;
    for (int w = w0; w < w1; ++w) {
        const unsigned mw = JbT[(size_t)w * B_N + b];
        nob += __popc(mw);
        const int wbase = w * 32;
        const float4* xp = Xt4 + (size_t)(w * 8) * B_N + b;
        #pragma unroll 4
        for (int g = 0; g < 8; ++g) {
            float4 xv = xp[(size_t)g * B_N];
            ACC_BODY(g * 4 + 0, xv.x);
            ACC_BODY(g * 4 + 1, xv.y);
            ACC_BODY(g * 4 + 2, xv.z);
            ACC_BODY(g * 4 + 3, xv.w);
        }
    }
    if (h) {  // tail word 24: bits 0..15 valid (packed zeros above)
        const unsigned mw = JbT[(size_t)24 * B_N + b];
        nob += __popc(mw);
        const int wbase = 768;
        const float4* xp = Xt4 + (size_t)(24 * 8) * B_N + b;
        #pragma unroll
        for (int g = 0; g < 4; ++g) {
            float4 xv = xp[(size_t)g * B_N];
            ACC_BODY(g * 4 + 0, xv.x);
            ACC_BODY(g * 4 + 1, xv.y);
            ACC_BODY(g * 4 + 2, xv.z);
            ACC_BODY(g * 4 + 3, xv.w);
        }
    }

    // merge the two d-halves through LDS (rec buffer is dead now)
    __syncthreads();
    float* red = smem;
    if (h) {
        float* o = &red[s * 33];
        #pragma unroll
        for (int t = 0; t < 21; ++t) o[t] = Pm[t];
        #pragma unroll
        for (int t = 0; t < 6; ++t) o[21 + t] = qv[t];
        o[27] = quad; o[28] = jld; o[29] = (float)nob;
    }
    __syncthreads();
    if (h == 0) {
        const float* o = &red[s * 33];
        #pragma unroll
        for (int t = 0; t < 21; ++t) Pm[t] += o[t];
        #pragma unroll
        for (int t = 0; t < 6; ++t) qv[t] += o[21 + t];
        quad += o[27]; jld += o[28];
        float nobs = (float)nob + o[29];

        // P = I + sum
        Pm[0] += 1.f; Pm[2] += 1.f; Pm[5] += 1.f; Pm[9] += 1.f; Pm[14] += 1.f; Pm[20] += 1.f;

        float Lm[21], rd[6], sumlog;
        chol6(Pm, Lm, rd, &sumlog);
        float y[6];
        #pragma unroll
        for (int j = 0; j < 6; ++j) {
            float sv = qv[j];
            #pragma unroll
            for (int m = 0; m < j; ++m) sv -= Lm[IDX(j,m)] * y[m];
            y[j] = sv * rd[j];
        }
        float yy = 0.f;
        #pragma unroll
        for (int j = 0; j < 6; ++j) yy += y[j] * y[j];
        float logdet = 2.f * sumlog + jld;
        float ll = -0.5f * ((quad - yy) + logdet + nobs * LOG2PI_F);
        float score = ll + PI[k];

        scores[(size_t)k * B_N + b] = score;
        float* pq = Pq + (size_t)k * 27 * B_N + b;
        #pragma unroll
        for (int t = 0; t < 21; ++t) pq[(size_t)t * B_N] = Pm[t];
        #pragma unroll
        for (int t = 0; t < 6; ++t) pq[(size_t)(21 + t) * B_N] = qv[t];
    }
}

// ---------- KC: argmax + latent solve per sample ----------
__global__ void k_select(const float* __restrict__ scores, const float* __restrict__ Pq,
                         int* __restrict__ csel, float* __restrict__ mzLz,
                         float* __restrict__ out) {
    int b = blockIdx.x * blockDim.x + threadIdx.x;
    if (b >= B_N) return;

    float best = scores[b];
    int bc = 0;
    for (int k = 1; k < K_N; ++k) {
        float s = scores[(size_t)k * B_N + b];
        if (s > best) { best = s; bc = k; }
    }
    csel[b] = bc;
    out[OUT_PW + b] = 1.0f;

    float Pm[21], qv[6];
    const float* pq = Pq + (size_t)bc * 27 * B_N + b;
    #pragma unroll
    for (int t = 0; t < 21; ++t) Pm[t] = pq[(size_t)t * B_N];
    #pragma unroll
    for (int t = 0; t < 6; ++t) qv[t] = pq[(size_t)(21 + t) * B_N];

    float Lm[21], rd[6], dummy;
    chol6(Pm, Lm, rd, &dummy);

    // forward: L y = q
    float y[6];
    #pragma unroll
    for (int j = 0; j < 6; ++j) {
        float s = qv[j];
        #pragma unroll
        for (int m = 0; m < j; ++m) s -= Lm[IDX(j,m)] * y[m];
        y[j] = s * rd[j];
    }
    // backward: L^T mz = y
    float mz[6];
    #pragma unroll
    for (int ii = 5; ii >= 0; --ii) {
        float s = y[ii];
        #pragma unroll
        for (int j = ii + 1; j < 6; ++j) s -= Lm[IDX(j,ii)] * mz[j];
        mz[ii] = s * rd[ii];
    }
    // Linv (packed lower)
    float Li[21];
    #pragma unroll
    for (int j = 0; j < 6; ++j) {
        Li[IDX(j,j)] = rd[j];
        #pragma unroll
        for (int i = j + 1; i < 6; ++i) {
            float s = 0.f;
            #pragma unroll
            for (int m = j; m < i; ++m) s += Lm[IDX(i,m)] * Li[IDX(m,j)];
            Li[IDX(i,j)] = -s * rd[i];
        }
    }
    // cov = Linv^T Linv (packed lower)
    float cov[21];
    #pragma unroll
    for (int i = 0; i < 6; ++i) {
        #pragma unroll
        for (int j = 0; j <= i; ++j) {
            float s = 0.f;
            #pragma unroll
            for (int m = i; m < 6; ++m) s += Li[IDX(m,i)] * Li[IDX(m,j)];
            cov[IDX(i,j)] = s;
        }
    }
    float Lz[21], rd2[6];
    chol6(cov, Lz, rd2, &dummy);

    float* o = mzLz + (size_t)b * 28;
    #pragma unroll
    for (int t = 0; t < 6; ++t) o[t] = mz[t];
    #pragma unroll
    for (int t = 0; t < 21; ++t) o[6 + t] = Lz[t];
}

// ---------- KD: write M, A_out, D_out ----------
__global__ __launch_bounds__(256) void k_output(
        const float* __restrict__ A, const float* __restrict__ MU,
        const float* __restrict__ logD, const int* __restrict__ csel,
        const float* __restrict__ mzLz, float* __restrict__ out) {
    __shared__ float smz[6];
    __shared__ float sLz[21];
    __shared__ int sc;
    int b = blockIdx.x;
    if (threadIdx.x == 0) sc = csel[b];
    if (threadIdx.x < 27) {
        float v = mzLz[(size_t)b * 28 + threadIdx.x];
        if (threadIdx.x < 6) smz[threadIdx.x] = v;
        else sLz[threadIdx.x - 6] = v;
    }
    __syncthreads();
    int c = sc;

    for (int d = threadIdx.x; d < D_FT; d += 256) {
        const float* ar = A + ((size_t)c * D_FT + d) * 6;
        float a[6];
        #pragma unroll
        for (int i = 0; i < 6; ++i) a[i] = ar[i];
        float mu = MU[(size_t)c * D_FT + d];
        float ld = logD[(size_t)c * D_FT + d];
        float m = mu;
        #pragma unroll
        for (int i = 0; i < 6; ++i) m += a[i] * smz[i];
        out[OUT_M + (size_t)b * D_FT + d] = m;
        out[OUT_D + (size_t)b * D_FT + d] = expf(ld);
        float* ao = out + OUT_A + ((size_t)b * D_FT + d) * 6;
        #pragma unroll
        for (int j = 0; j < 6; ++j) {
            float s = 0.f;
            #pragma unroll
            for (int i = j; i < 6; ++i) s += a[i] * sLz[IDX(i,j)];
            ao[j] = s;
        }
    }
}

extern "C" void kernel_launch(void* const* d_in, const int* in_sizes, int n_in,
                              void* d_out, int out_size, void* d_ws, size_t ws_size,
                              hipStream_t stream) {
    (void)in_sizes; (void)n_in; (void)out_size; (void)ws_size;
    const float* X    = (const float*)d_in[0];
    const int*   J    = (const int*)d_in[1];
    const float* MU   = (const float*)d_in[2];
    const float* A    = (const float*)d_in[3];
    const float* logD = (const float*)d_in[4];
    const float* PI   = (const float*)d_in[5];
    float* out = (float*)d_out;
    float* ws  = (float*)d_ws;

    float*    scores = ws + WS_SCORES;
    float*    Pq     = ws + WS_PQ;
    int*      csel   = (int*)(ws + WS_C);
    float*    mzLz   = ws + WS_MZLZ;
    float4*   Xt4    = (float4*)(ws + WS_XT);
    unsigned* JbT    = (unsigned*)(ws + WS_JBT);

    dim3 g0((D_FT / 4 + 31) / 32, B_N / 32), b0(32, 32);
    k_transpose4<<<g0, b0, 0, stream>>>(X, Xt4);

    k_packbits<<<(B_N * 32) / 256, 256, 0, stream>>>(J, JbT);

    k_accum<<<16 * K_N, 256, 0, stream>>>(Xt4, JbT, A, MU, logD, PI, scores, Pq);

    k_select<<<B_N / 256, 256, 0, stream>>>(scores, Pq, csel, mzLz, out);

    k_output<<<B_N, 256, 0, stream>>>(A, MU, logD, csel, mzLz, out);
}